// Round 4
// baseline (766.437 us; speedup 1.0000x reference)
//
#include <hip/hip_runtime.h>
#include <math.h>

#define HIDDEN 4096
#define NEXP   128
#define TOPK   8
#define BM     64    // tokens per block
#define BN     128   // experts per block (all)
#define BK     64    // K chunk
#define SA     68    // LDS stride A tile (mult of 4 for aligned float4)
#define SB     132   // LDS stride B tile
#define SS     132   // epilogue score-row stride
#define NCHUNK (HIDDEN / BK)   // 64

// smem: As[BK][SA] (4352 f) + Bs[BK][SB] (8448 f) = 12800 floats = 51.2 KB
// epilogue Ss[BM][SS] = 8448 floats aliases the same buffer.
#define SMEM_FLOATS 12800

// Bit-identical-to-round-1 fp32 logits: each (token,expert) output is a single
// fp32 accumulator updated by fmaf with k ascending 0..4095. Tiling around the
// chains is free; the chain itself is what the reference check is sensitive to.
__global__ __launch_bounds__(256, 1) void router_kernel(
    const float* __restrict__ h,     // [T, HIDDEN]
    const float* __restrict__ w,     // [NEXP, HIDDEN]
    const float* __restrict__ bias,  // [NEXP]
    float* __restrict__ out,         // [T*8] indices (as float) ++ [T*8] weights
    int T)
{
    __shared__ float smem[SMEM_FLOATS];
    float* As = smem;            // [BK][SA]  transposed: As[k][token]
    float* Bs = smem + BK * SA;  // [BK][SB]  transposed: Bs[k][expert]

    const int tid  = threadIdx.x;
    const int row0 = blockIdx.x * BM;
    const int tm   = tid >> 5;   // 0..7 : tokens 8*tm .. 8*tm+7
    const int tn   = tid & 31;   // 0..31: experts 4*tn .. 4*tn+3

    float acc[8][4];
#pragma unroll
    for (int i = 0; i < 8; ++i)
#pragma unroll
        for (int j = 0; j < 4; ++j) acc[i][j] = 0.0f;

    // staging decomposition: item id -> (row r, float4 kq)
    // A tile: 64 rows x 16 float4 = 1024 items (4/thread)
    // B tile: 128 rows x 16 float4 = 2048 items (8/thread)
    const int ra  = (tid + 0) >> 4;  // pattern: r = id>>4, kq = id&15
    const int kqa = tid & 15;

    // ---- prefetch chunk 0 into registers
    float4 pa[4], pb[8];
#pragma unroll
    for (int i = 0; i < 4; ++i) {
        const int id = tid + 256 * i;
        pa[i] = *(const float4*)(h + (size_t)(row0 + (id >> 4)) * HIDDEN + 4 * (id & 15));
    }
#pragma unroll
    for (int i = 0; i < 8; ++i) {
        const int id = tid + 256 * i;
        pb[i] = *(const float4*)(w + (size_t)(id >> 4) * HIDDEN + 4 * (id & 15));
    }
    (void)ra; (void)kqa;

    for (int c = 0; c < NCHUNK; ++c) {
        __syncthreads();   // readers of the previous chunk are done with As/Bs
        // ---- scatter prefetched regs -> transposed LDS tiles
#pragma unroll
        for (int i = 0; i < 4; ++i) {
            const int id = tid + 256 * i;
            const int r  = id >> 4;
            const int k4 = 4 * (id & 15);
            As[(k4 + 0) * SA + r] = pa[i].x;
            As[(k4 + 1) * SA + r] = pa[i].y;
            As[(k4 + 2) * SA + r] = pa[i].z;
            As[(k4 + 3) * SA + r] = pa[i].w;
        }
#pragma unroll
        for (int i = 0; i < 8; ++i) {
            const int id = tid + 256 * i;
            const int r  = id >> 4;
            const int k4 = 4 * (id & 15);
            Bs[(k4 + 0) * SB + r] = pb[i].x;
            Bs[(k4 + 1) * SB + r] = pb[i].y;
            Bs[(k4 + 2) * SB + r] = pb[i].z;
            Bs[(k4 + 3) * SB + r] = pb[i].w;
        }
        __syncthreads();   // stores visible to all waves

        // ---- issue next chunk's global loads (in flight during compute)
        if (c + 1 < NCHUNK) {
            const int k0n = (c + 1) * BK;
#pragma unroll
            for (int i = 0; i < 4; ++i) {
                const int id = tid + 256 * i;
                pa[i] = *(const float4*)(h + (size_t)(row0 + (id >> 4)) * HIDDEN + k0n + 4 * (id & 15));
            }
#pragma unroll
            for (int i = 0; i < 8; ++i) {
                const int id = tid + 256 * i;
                pb[i] = *(const float4*)(w + (size_t)(id >> 4) * HIDDEN + k0n + 4 * (id & 15));
            }
        }

        // ---- compute: 64 k-steps, 32 fmaf each; per-acc chain k ascending
#pragma unroll 8
        for (int k = 0; k < BK; ++k) {
            const float4 a0 = *(const float4*)(As + k * SA + 8 * tm);
            const float4 a1 = *(const float4*)(As + k * SA + 8 * tm + 4);
            const float4 b  = *(const float4*)(Bs + k * SB + 4 * tn);
            const float av[8] = {a0.x, a0.y, a0.z, a0.w, a1.x, a1.y, a1.z, a1.w};
            const float bv[4] = {b.x, b.y, b.z, b.w};
#pragma unroll
            for (int i = 0; i < 8; ++i)
#pragma unroll
                for (int j = 0; j < 4; ++j)
                    acc[i][j] = fmaf(av[i], bv[j], acc[i][j]);
        }
    }

    // ---- write logits to shared score buffer (aliases As/Bs)
    __syncthreads();
    float* Ss = smem;  // [BM][SS]
#pragma unroll
    for (int i = 0; i < 8; ++i) {
        const int t = 8 * tm + i;
        *(float4*)(Ss + t * SS + 4 * tn) = make_float4(acc[i][0], acc[i][1], acc[i][2], acc[i][3]);
    }
    __syncthreads();

    // ---- top-8 epilogue: verbatim round-1 (passed) logic
    const int wave = tid >> 6;
    const int lane = tid & 63;
    const float bb0 = bias[lane];
    const float bb1 = bias[lane + 64];

    for (int t = wave; t < BM; t += 4) {
        const float lg0 = Ss[t * SS + lane];
        const float lg1 = Ss[t * SS + 64 + lane];
        const float s0 = 1.0f / (1.0f + expf(-lg0));  // raw sigmoid score
        const float s1 = 1.0f / (1.0f + expf(-lg1));
        float c0 = s0 + bb0;                          // bias-corrected (selection)
        float c1 = s1 + bb1;

        int   sel_i[TOPK];
        float sel_r[TOPK];
        float rsum = 0.0f;
#pragma unroll
        for (int j = 0; j < TOPK; ++j) {
            const bool take0 = (c0 >= c1);            // tie -> smaller expert index
            float v  = take0 ? c0 : c1;
            float rr = take0 ? s0 : s1;
            int   ii = take0 ? lane : lane + 64;
#pragma unroll
            for (int off = 32; off > 0; off >>= 1) {  // lexicographic argmax
                const float ov  = __shfl_xor(v, off, 64);
                const float orr = __shfl_xor(rr, off, 64);
                const int   oi  = __shfl_xor(ii, off, 64);
                if (ov > v || (ov == v && oi < ii)) { v = ov; rr = orr; ii = oi; }
            }
            sel_i[j] = ii;
            sel_r[j] = rr;
            rsum += rr;
            if (ii == lane)      c0 = -__builtin_inff();
            if (ii == lane + 64) c1 = -__builtin_inff();
        }
        if (lane == 0) {
            const float inv = 1.0f / (rsum + 1e-20f);
            const size_t tok = (size_t)(row0 + t);
#pragma unroll
            for (int j = 0; j < TOPK; ++j) {
                out[tok * TOPK + j]                    = (float)sel_i[j];
                out[(size_t)T * TOPK + tok * TOPK + j] = sel_r[j] * inv;
            }
        }
    }
}

extern "C" void kernel_launch(void* const* d_in, const int* in_sizes, int n_in,
                              void* d_out, int out_size, void* d_ws, size_t ws_size,
                              hipStream_t stream) {
    const float* h    = (const float*)d_in[0];
    const float* w    = (const float*)d_in[1];
    const float* bias = (const float*)d_in[2];
    float* out = (float*)d_out;
    const int T = in_sizes[0] / HIDDEN;  // 16384

    hipLaunchKernelGGL(router_kernel, dim3(T / BM), dim3(256), 0, stream,
                       h, w, bias, out, T);
}